// Round 19
// baseline (269.077 us; speedup 1.0000x reference)
//
#include <hip/hip_runtime.h>
#include <hip/hip_bf16.h>
#include <stdint.h>

#define B_ 2
#define N_ 2048
#define D_ 1024
#define H_ 16
#define MM 4096
#define NN 1024
#define KK 1024

typedef __bf16 bf16;
typedef __bf16 bf16x8 __attribute__((ext_vector_type(8)));
typedef float f32x4 __attribute__((ext_vector_type(4)));

struct __align__(8) bf4 { bf16 v[4]; };

#define LDS_STRIDE 144   // 64 bf16 + 8 pad (Q/K rows)
#define PSTR 272         // 128 bf16 + 8 pad (P/V rows)
#define LOG2E 1.44269504088896340736f

// ---------------------------------------------------------------- prep (wtt x4 + mask bits, one launch)
__global__ __launch_bounds__(256) void k_prep(const float* __restrict__ Wq,
                                              const float* __restrict__ Wk,
                                              const float* __restrict__ Wv,
                                              const float* __restrict__ Wo,
                                              const int* __restrict__ mask,
                                              bf16* __restrict__ WqT,
                                              bf16* __restrict__ WkT,
                                              bf16* __restrict__ WvT,
                                              bf16* __restrict__ WoT,
                                              uint32_t* __restrict__ bits) {
    __shared__ float tl[32][33];
    const int bid = blockIdx.x;
    if (bid < 4096) {
        const int z = bid >> 10, t = bid & 1023;
        const float* W = z == 0 ? Wq : z == 1 ? Wk : z == 2 ? Wv : Wo;
        bf16* Wt = z == 0 ? WqT : z == 1 ? WkT : z == 2 ? WvT : WoT;
        const int bx = (t & 31) * 32, by = (t >> 5) * 32;
        const int tx = threadIdx.x & 31, ty = threadIdx.x >> 5;
#pragma unroll
        for (int j = 0; j < 32; j += 8)
            tl[ty + j][tx] = W[(size_t)(by + ty + j) * 1024 + bx + tx];
        __syncthreads();
#pragma unroll
        for (int j = 0; j < 32; j += 8)
            Wt[(size_t)(bx + ty + j) * 1024 + by + tx] = (bf16)tl[tx][ty + j];
    } else {
        size_t flat = (size_t)(bid - 4096) * 256 + threadIdx.x;
        int col = (int)(flat & (N_ - 1));
        int row = (int)((flat >> 11) & (N_ - 1));
        bool ok = (mask[flat] != 0) && (col <= row);
        unsigned long long bal = __ballot(ok);
        if ((threadIdx.x & 63) == 0)
            *(unsigned long long*)(bits + (flat >> 5)) = bal;
    }
}

// ---------------------------------------------------------------- GEMM core (kernel-B)
template <bool AF32>
__device__ __forceinline__ void kb_core(const void* __restrict__ Av,
                                        const bf16* __restrict__ Bt,
                                        int bm0, int bn0,
                                        char* AsB, char* BsB,
                                        f32x4 (&acc)[4][2]) {
    const int tid = threadIdx.x, lane = tid & 63, w = tid >> 6;
    const int g = lane >> 4, li = lane & 15;
    const int srow = tid >> 3, sc = tid & 7;
    const bf16* Ab = (const bf16*)Av;
    const float* Af = (const float*)Av;

    f32x4 zz = {0.f, 0.f, 0.f, 0.f};
#pragma unroll
    for (int mf = 0; mf < 4; ++mf)
#pragma unroll
        for (int nf = 0; nf < 2; ++nf) acc[mf][nf] = zz;

    f32x4 pa0[2], pa1[2];
    bf16x8 pab[2];
    bf16x8 pb[4];

    auto issueA = [&](int k0) {
        if constexpr (AF32) {
#pragma unroll
            for (int i = 0; i < 2; ++i) {
                const float* s = Af + (size_t)(bm0 + srow + 32 * i) * KK + k0 + sc * 8;
                pa0[i] = *(const f32x4*)s;
                pa1[i] = *(const f32x4*)(s + 4);
            }
        } else {
#pragma unroll
            for (int i = 0; i < 2; ++i)
                pab[i] = *(const bf16x8*)(Ab + (size_t)(bm0 + srow + 32 * i) * KK + k0 + sc * 8);
        }
    };
    auto issueB = [&](int k0) {
#pragma unroll
        for (int i = 0; i < 4; ++i)
            pb[i] = *(const bf16x8*)(Bt + (size_t)(bn0 + srow + 32 * i) * KK + k0 + sc * 8);
    };
    auto writeS = [&]() {
#pragma unroll
        for (int i = 0; i < 2; ++i) {
            bf16x8 t;
            if constexpr (AF32) {
#pragma unroll
                for (int j = 0; j < 4; ++j) {
                    t[j] = (bf16)pa0[i][j];
                    t[4 + j] = (bf16)pa1[i][j];
                }
            } else {
                t = pab[i];
            }
            *(bf16x8*)(AsB + (srow + 32 * i) * LDS_STRIDE + sc * 16) = t;
        }
#pragma unroll
        for (int i = 0; i < 4; ++i)
            *(bf16x8*)(BsB + (srow + 32 * i) * LDS_STRIDE + sc * 16) = pb[i];
    };

    issueA(0);
    issueB(0);
    for (int k0 = 0; k0 < KK; k0 += 64) {
        __syncthreads();
        writeS();
        int kn = (k0 + 64 < KK) ? k0 + 64 : k0;
        issueA(kn);
        issueB(kn);
        __syncthreads();
#pragma unroll
        for (int kk = 0; kk < 2; ++kk) {
            const int kb = kk * 64 + (g << 4);
            bf16x8 bfr[2];
#pragma unroll
            for (int nf = 0; nf < 2; ++nf) {
                int rn = w * 32 + nf * 16 + li;
                bfr[nf] = *(const bf16x8*)(BsB + rn * LDS_STRIDE + kb);
            }
#pragma unroll
            for (int mf = 0; mf < 4; ++mf) {
                int rm = mf * 16 + li;
                bf16x8 afr = *(const bf16x8*)(AsB + rm * LDS_STRIDE + kb);
                acc[mf][0] = __builtin_amdgcn_mfma_f32_16x16x32_bf16(
                    afr, bfr[0], acc[mf][0], 0, 0, 0);
                acc[mf][1] = __builtin_amdgcn_mfma_f32_16x16x32_bf16(
                    afr, bfr[1], acc[mf][1], 0, 0, 0);
            }
        }
    }
}

// fused Q/K/V projections: one launch, grid (64, 8, 3)
__global__ __launch_bounds__(256) void k_proj3(const float* __restrict__ q,
                                               const float* __restrict__ k,
                                               const float* __restrict__ v,
                                               const bf16* __restrict__ WqT,
                                               const bf16* __restrict__ WkT,
                                               const bf16* __restrict__ WvT,
                                               bf16* __restrict__ Qh,
                                               bf16* __restrict__ Kh,
                                               bf16* __restrict__ Vt) {
    __shared__ __align__(16) char AsB[64 * LDS_STRIDE];
    __shared__ __align__(16) char BsB[128 * LDS_STRIDE];
    const int z = blockIdx.z;
    const float* A = z == 0 ? q : z == 1 ? k : v;
    const bf16* Bt = z == 0 ? WqT : z == 1 ? WkT : WvT;
    const float scale = (z == 0) ? 0.125f * LOG2E : 1.0f;
    const int bm0 = blockIdx.x * 64, bn0 = blockIdx.y * 128;

    f32x4 acc[4][2];
    kb_core<true>(A, Bt, bm0, bn0, AsB, BsB, acc);

    const int tid = threadIdx.x, lane = tid & 63, w = tid >> 6;
    const int g = lane >> 4, li = lane & 15;

    if (z < 2) {
        bf16* C = (z == 0) ? Qh : Kh;
#pragma unroll
        for (int mf = 0; mf < 4; ++mf)
#pragma unroll
            for (int nf = 0; nf < 2; ++nf) {
                int n = bn0 + w * 32 + nf * 16 + li;
                int m0 = bm0 + mf * 16 + (g << 2);
#pragma unroll
                for (int r = 0; r < 4; ++r)
                    C[(size_t)(m0 + r) * NN + n] = (bf16)(acc[mf][nf][r] * scale);
            }
    } else {
#pragma unroll
        for (int mf = 0; mf < 4; ++mf)
#pragma unroll
            for (int nf = 0; nf < 2; ++nf) {
                int n = bn0 + w * 32 + nf * 16 + li;
                int m0 = bm0 + mf * 16 + (g << 2);
                int bq = m0 >> 11, tok = m0 & (N_ - 1);
                int hh = n >> 6, dv = n & 63;
                bf4 val;
#pragma unroll
                for (int r = 0; r < 4; ++r) val.v[r] = (bf16)acc[mf][nf][r];
                *(bf4*)(Vt + ((size_t)((bq * H_ + hh) * 64 + dv)) * N_ + tok) = val;
            }
    }
}

// output GEMM: out = Ob @ WoT^T + resid
__global__ __launch_bounds__(256) void k_out(const bf16* __restrict__ Ob,
                                             const bf16* __restrict__ WoT,
                                             float* __restrict__ outp,
                                             const float* __restrict__ resid) {
    __shared__ __align__(16) char AsB[64 * LDS_STRIDE];
    __shared__ __align__(16) char BsB[128 * LDS_STRIDE];
    const int bm0 = blockIdx.x * 64, bn0 = blockIdx.y * 128;

    f32x4 acc[4][2];
    kb_core<false>(Ob, WoT, bm0, bn0, AsB, BsB, acc);

    const int tid = threadIdx.x, lane = tid & 63, w = tid >> 6;
    const int g = lane >> 4, li = lane & 15;
#pragma unroll
    for (int mf = 0; mf < 4; ++mf)
#pragma unroll
        for (int nf = 0; nf < 2; ++nf) {
            int n = bn0 + w * 32 + nf * 16 + li;
            int m0 = bm0 + mf * 16 + (g << 2);
#pragma unroll
            for (int r = 0; r < 4; ++r) {
                size_t ix = (size_t)(m0 + r) * NN + n;
                outp[ix] = acc[mf][nf][r] + resid[ix];
            }
        }
}

// ---------------------------------------------------------------- attention
// R16 structure + deferred attn stores: round jt's P stored at top of round
// jt+1 (full QK^T+softmax+PV window in flight before the next barrier drain).
__global__ __launch_bounds__(256) void k_attn(const bf16* __restrict__ Qh,
                                              const bf16* __restrict__ Kh,
                                              const bf16* __restrict__ Vt,
                                              const uint32_t* __restrict__ bits,
                                              float* __restrict__ attnp,
                                              bf16* __restrict__ Ob) {
    __shared__ __align__(16) char Qs[64 * LDS_STRIDE];    //  9216
    __shared__ __align__(16) char Ks[128 * LDS_STRIDE];   // 18432
    __shared__ __align__(16) char Vs[64 * PSTR];          // 17408
    __shared__ __align__(16) char Ps[64 * PSTR];          // 17408
    const int tid = threadIdx.x, lane = tid & 63, w = tid >> 6;
    const int g = lane >> 4, li = lane & 15;
    const int p = blockIdx.x, h = blockIdx.y, b = blockIdx.z;
    const int srow = tid >> 3, sc = tid & 7;
    const int myrow = w * 16 + li;

    const size_t kbase = ((size_t)b * N_) * D_ + h * 64;
    const size_t vbase = ((size_t)(b * H_ + h) * 64) * N_;
    f32x4 zz = {0.f, 0.f, 0.f, 0.f};

    bf16x8 kr[4], vr[4];
    auto loadK = [&](int jt) {
#pragma unroll
        for (int i = 0; i < 4; ++i)
            kr[i] = *(const bf16x8*)(Kh + kbase +
                (size_t)(jt * 128 + srow + 32 * i) * D_ + sc * 8);
    };
    auto writeK = [&]() {
#pragma unroll
        for (int i = 0; i < 4; ++i)
            *(bf16x8*)(Ks + (srow + 32 * i) * LDS_STRIDE + sc * 16) = kr[i];
    };
    auto loadV = [&](int jt) {
#pragma unroll
        for (int c = 0; c < 4; ++c) {
            int row = srow + 32 * (c & 1);
            int cc = sc + 8 * (c >> 1);
            vr[c] = *(const bf16x8*)(Vt + vbase + (size_t)row * N_ + jt * 128 + cc * 8);
        }
    };
    auto writeV = [&]() {
#pragma unroll
        for (int c = 0; c < 4; ++c) {
            int row = srow + 32 * (c & 1);
            int cc = sc + 8 * (c >> 1);
            *(bf16x8*)(Vs + row * PSTR + cc * 16) = vr[c];
        }
    };

    for (int half = 0; half < 2; ++half) {
        const int qt = half ? (31 - p) : p;
        const int i0 = qt << 6;
        const int R = (qt + 2) >> 1;
        const size_t abase = (((size_t)b * H_ + h) * N_ + i0) * (size_t)N_;

        __syncthreads();
        {
            const bf16* qsrc = Qh + kbase + (size_t)(i0 + srow) * D_ + sc * 8;
            bf16x8 t0 = *(const bf16x8*)qsrc;
            bf16x8 t1 = *(const bf16x8*)(qsrc + (size_t)32 * D_);
            *(bf16x8*)(Qs + srow * LDS_STRIDE + sc * 16) = t0;
            *(bf16x8*)(Qs + (srow + 32) * LDS_STRIDE + sc * 16) = t1;
        }
        const uint32_t* mrow = bits + (((size_t)b * N_ + i0 + myrow) << 6);

        // ================= pass A: row stats =================
        float m = -1e30f, l = 0.f;
        loadK(0);
        for (int jt = 0; jt < R; ++jt) {
            __syncthreads();
            writeK();
            loadK((jt + 1 < R) ? jt + 1 : jt);
            uint4 mw = *(const uint4*)(mrow + (jt << 2));
            __syncthreads();

            f32x4 s[8];
#pragma unroll
            for (int mf = 0; mf < 8; ++mf) s[mf] = zz;
            __builtin_amdgcn_s_setprio(1);
#pragma unroll
            for (int kk = 0; kk < 2; ++kk) {
                const int kb = kk * 64 + (g << 4);
                bf16x8 qf = *(const bf16x8*)(Qs + myrow * LDS_STRIDE + kb);
#pragma unroll
                for (int mf = 0; mf < 8; ++mf) {
                    bf16x8 kf = *(const bf16x8*)(Ks + (mf * 16 + li) * LDS_STRIDE + kb);
                    s[mf] = __builtin_amdgcn_mfma_f32_16x16x32_bf16(kf, qf, s[mf], 0, 0, 0);
                }
            }
            __builtin_amdgcn_s_setprio(0);
            float tmax = m;
#pragma unroll
            for (int mf = 0; mf < 8; ++mf) {
                uint32_t wsel = (mf < 2) ? mw.x : (mf < 4) ? mw.y : (mf < 6) ? mw.z : mw.w;
#pragma unroll
                for (int r = 0; r < 4; ++r) {
                    int sh = (mf & 1) * 16 + g * 4 + r;
                    float xv = ((wsel >> sh) & 1) ? s[mf][r] : -1e9f;
                    s[mf][r] = xv;
                    tmax = fmaxf(tmax, xv);
                }
            }
            tmax = fmaxf(tmax, __shfl_xor(tmax, 16));
            tmax = fmaxf(tmax, __shfl_xor(tmax, 32));
            float ps = 0.f;
#pragma unroll
            for (int mf = 0; mf < 8; ++mf)
#pragma unroll
                for (int r = 0; r < 4; ++r) ps += exp2f(s[mf][r] - tmax);
            ps += __shfl_xor(ps, 16);
            ps += __shfl_xor(ps, 32);
            l = l * exp2f(m - tmax) + ps;
            m = tmax;
        }
        const float ml = m + __log2f(l);

        // ================= pass B: P + O (deferred stores) =================
        f32x4 oacc[4];
#pragma unroll
        for (int nf = 0; nf < 4; ++nf) oacc[nf] = zz;
        f32x4 pend[8];

        loadK(0);
        loadV(0);
        for (int jt = 0; jt < R; ++jt) {
            __syncthreads();
            writeK();
            writeV();
            {
                int jn = (jt + 1 < R) ? jt + 1 : jt;
                loadK(jn);
                loadV(jn);
            }
            uint4 mw = *(const uint4*)(mrow + (jt << 2));
            __syncthreads();

            // issue previous round's attn stores now: full round in flight
            if (jt > 0) {
                float* dst = attnp + abase + (size_t)myrow * N_ + ((jt - 1) << 7);
#pragma unroll
                for (int mf = 0; mf < 8; ++mf)
                    *(f32x4*)(dst + mf * 16 + g * 4) = pend[mf];
            }

            f32x4 s[8];
#pragma unroll
            for (int mf = 0; mf < 8; ++mf) s[mf] = zz;
            __builtin_amdgcn_s_setprio(1);
#pragma unroll
            for (int kk = 0; kk < 2; ++kk) {
                const int kb = kk * 64 + (g << 4);
                bf16x8 qf = *(const bf16x8*)(Qs + myrow * LDS_STRIDE + kb);
#pragma unroll
                for (int mf = 0; mf < 8; ++mf) {
                    bf16x8 kf = *(const bf16x8*)(Ks + (mf * 16 + li) * LDS_STRIDE + kb);
                    s[mf] = __builtin_amdgcn_mfma_f32_16x16x32_bf16(kf, qf, s[mf], 0, 0, 0);
                }
            }
            __builtin_amdgcn_s_setprio(0);

#pragma unroll
            for (int mf = 0; mf < 8; ++mf) {
                uint32_t wsel = (mf < 2) ? mw.x : (mf < 4) ? mw.y : (mf < 6) ? mw.z : mw.w;
#pragma unroll
                for (int r = 0; r < 4; ++r) {
                    int sh = (mf & 1) * 16 + g * 4 + r;
                    float xv = ((wsel >> sh) & 1) ? s[mf][r] : -1e9f;
                    s[mf][r] = exp2f(xv - ml);
                }
                bf4 pk;
#pragma unroll
                for (int r = 0; r < 4; ++r) pk.v[r] = (bf16)s[mf][r];
                *(bf4*)(Ps + myrow * PSTR + (mf * 16 + g * 4) * 2) = pk;
            }
            __builtin_amdgcn_s_setprio(1);
#pragma unroll
            for (int kk = 0; kk < 4; ++kk) {
                const int kb = kk * 64 + (g << 4);
                bf16x8 pf = *(const bf16x8*)(Ps + myrow * PSTR + kb);
#pragma unroll
                for (int nf = 0; nf < 4; ++nf) {
                    bf16x8 vf = *(const bf16x8*)(Vs + (nf * 16 + li) * PSTR + kb);
                    oacc[nf] = __builtin_amdgcn_mfma_f32_16x16x32_bf16(pf, vf, oacc[nf], 0, 0, 0);
                }
            }
            __builtin_amdgcn_s_setprio(0);
            // hand off: previous stores had the whole round to read pend
#pragma unroll
            for (int mf = 0; mf < 8; ++mf) pend[mf] = s[mf];
        }
        // flush final round's P
        {
            float* dst = attnp + abase + (size_t)myrow * N_ + ((R - 1) << 7);
#pragma unroll
            for (int mf = 0; mf < 8; ++mf)
                *(f32x4*)(dst + mf * 16 + g * 4) = pend[mf];
        }
        // O store
#pragma unroll
        for (int nf = 0; nf < 4; ++nf)
#pragma unroll
            for (int r = 0; r < 4; ++r) {
                int gi = i0 + w * 16 + g * 4 + r;
                Ob[((size_t)(b * N_ + gi)) * D_ + h * 64 + nf * 16 + li] = (bf16)oacc[nf][r];
            }
        // zero-fill cols [R*128, N)
        int zc0 = R << 7;
        if (zc0 < N_) {
            int r = tid >> 2, tc = tid & 3;
            f32x4 z = zz;
            for (int c = zc0 + tc * 4; c < N_; c += 16)
                *(f32x4*)(attnp + abase + (size_t)r * N_ + c) = z;
        }
    }
}

// ---------------------------------------------------------------- layernorm
__global__ __launch_bounds__(256) void k_ln(float* __restrict__ out,
                                            const float* __restrict__ gamma,
                                            const float* __restrict__ beta) {
    const int row = blockIdx.x, t = threadIdx.x, lane = t & 63, w = t >> 6;
    float* p = out + (size_t)row * D_;
    f32x4 x = *(const f32x4*)(p + t * 4);
    float s = x[0] + x[1] + x[2] + x[3];
    float s2 = x[0] * x[0] + x[1] * x[1] + x[2] * x[2] + x[3] * x[3];
#pragma unroll
    for (int o = 1; o < 64; o <<= 1) {
        s += __shfl_xor(s, o);
        s2 += __shfl_xor(s2, o);
    }
    __shared__ float r1[4], r2[4];
    if (lane == 0) { r1[w] = s; r2[w] = s2; }
    __syncthreads();
    s = r1[0] + r1[1] + r1[2] + r1[3];
    s2 = r2[0] + r2[1] + r2[2] + r2[3];
    float mean = s * (1.f / D_);
    float var = s2 * (1.f / D_) - mean * mean;
    float rstd = rsqrtf(var + 1e-6f);
    f32x4 gv = *(const f32x4*)(gamma + t * 4);
    f32x4 bv = *(const f32x4*)(beta + t * 4);
    f32x4 y;
#pragma unroll
    for (int c = 0; c < 4; ++c) y[c] = (x[c] - mean) * rstd * gv[c] + bv[c];
    *(f32x4*)(p + t * 4) = y;
}

// ---------------------------------------------------------------- launch
extern "C" void kernel_launch(void* const* d_in, const int* in_sizes, int n_in,
                              void* d_out, int out_size, void* d_ws,
                              size_t ws_size, hipStream_t stream) {
    (void)in_sizes; (void)n_in; (void)out_size; (void)ws_size;
    const float* q = (const float*)d_in[0];
    const float* k = (const float*)d_in[1];
    const float* v = (const float*)d_in[2];
    const int* msk = (const int*)d_in[3];
    const float* Wq = (const float*)d_in[4];
    const float* Wk = (const float*)d_in[5];
    const float* Wv = (const float*)d_in[6];
    const float* Wo = (const float*)d_in[7];
    const float* gamma = (const float*)d_in[8];
    const float* beta = (const float*)d_in[9];

    float* outp = (float*)d_out;
    float* attnp = outp + (size_t)B_ * N_ * D_;

    const size_t U = (size_t)B_ * N_ * D_;
    const size_t W1 = (size_t)D_ * D_;
    bf16* ws = (bf16*)d_ws;
    bf16* WqT = ws;  ws += W1;
    bf16* WkT = ws;  ws += W1;
    bf16* WvT = ws;  ws += W1;
    bf16* WoT = ws;  ws += W1;
    bf16* Qh = ws;   ws += U;
    bf16* Kh = ws;   ws += U;
    bf16* Vt = ws;   ws += U;   // (B,H,DV,N)
    bf16* Ob = ws;   ws += U;
    uint32_t* bits = (uint32_t*)ws;  // 1 MB

    k_prep<<<4096 + (B_ * N_ * N_ / 256), 256, 0, stream>>>(
        Wq, Wk, Wv, Wo, msk, WqT, WkT, WvT, WoT, bits);

    k_proj3<<<dim3(MM / 64, NN / 128, 3), 256, 0, stream>>>(q, k, v, WqT, WkT, WvT, Qh, Kh, Vt);

    k_attn<<<dim3(16, H_, B_), 256, 0, stream>>>(Qh, Kh, Vt, bits, attnp, Ob);

    k_out<<<dim3(MM / 64, NN / 128), 256, 0, stream>>>(Ob, WoT, outp, q);

    k_ln<<<B_ * N_, 256, 0, stream>>>(outp, gamma, beta);
}

// Round 20
// 259.328 us; speedup vs baseline: 1.0376x; 1.0376x over previous
//
#include <hip/hip_runtime.h>
#include <hip/hip_bf16.h>
#include <stdint.h>

#define B_ 2
#define N_ 2048
#define D_ 1024
#define H_ 16
#define MM 4096
#define NN 1024
#define KK 1024

typedef __bf16 bf16;
typedef __bf16 bf16x8 __attribute__((ext_vector_type(8)));
typedef float f32x4 __attribute__((ext_vector_type(4)));

struct __align__(8) bf4 { bf16 v[4]; };

#define LDS_STRIDE 144   // 64 bf16 + 8 pad (Q/K rows)
#define PSTR 272         // 128 bf16 + 8 pad (P/V rows)
#define LOG2E 1.44269504088896340736f

// ---------------------------------------------------------------- prep (wtt x4 + mask bits, one launch)
__global__ __launch_bounds__(256) void k_prep(const float* __restrict__ Wq,
                                              const float* __restrict__ Wk,
                                              const float* __restrict__ Wv,
                                              const float* __restrict__ Wo,
                                              const int* __restrict__ mask,
                                              bf16* __restrict__ WqT,
                                              bf16* __restrict__ WkT,
                                              bf16* __restrict__ WvT,
                                              bf16* __restrict__ WoT,
                                              uint32_t* __restrict__ bits) {
    __shared__ float tl[32][33];
    const int bid = blockIdx.x;
    if (bid < 4096) {
        // weight transpose: Wt[n][k] = (bf16)W[k][n]
        const int z = bid >> 10, t = bid & 1023;
        const float* W = z == 0 ? Wq : z == 1 ? Wk : z == 2 ? Wv : Wo;
        bf16* Wt = z == 0 ? WqT : z == 1 ? WkT : z == 2 ? WvT : WoT;
        const int bx = (t & 31) * 32, by = (t >> 5) * 32;
        const int tx = threadIdx.x & 31, ty = threadIdx.x >> 5;  // 32 x 8
#pragma unroll
        for (int j = 0; j < 32; j += 8)
            tl[ty + j][tx] = W[(size_t)(by + ty + j) * 1024 + bx + tx];
        __syncthreads();
#pragma unroll
        for (int j = 0; j < 32; j += 8)
            Wt[(size_t)(bx + ty + j) * 1024 + by + tx] = (bf16)tl[tx][ty + j];
    } else {
        // mask bits: bit j = (mask != 0) && (col <= row)
        size_t flat = (size_t)(bid - 4096) * 256 + threadIdx.x;
        int col = (int)(flat & (N_ - 1));
        int row = (int)((flat >> 11) & (N_ - 1));
        bool ok = (mask[flat] != 0) && (col <= row);
        unsigned long long bal = __ballot(ok);
        if ((threadIdx.x & 63) == 0)
            *(unsigned long long*)(bits + (flat >> 5)) = bal;
    }
}

// ---------------------------------------------------------------- GEMM core (kernel-B)
template <bool AF32>
__device__ __forceinline__ void kb_core(const void* __restrict__ Av,
                                        const bf16* __restrict__ Bt,
                                        int bm0, int bn0,
                                        char* AsB, char* BsB,
                                        f32x4 (&acc)[4][2]) {
    const int tid = threadIdx.x, lane = tid & 63, w = tid >> 6;
    const int g = lane >> 4, li = lane & 15;
    const int srow = tid >> 3, sc = tid & 7;
    const bf16* Ab = (const bf16*)Av;
    const float* Af = (const float*)Av;

    f32x4 zz = {0.f, 0.f, 0.f, 0.f};
#pragma unroll
    for (int mf = 0; mf < 4; ++mf)
#pragma unroll
        for (int nf = 0; nf < 2; ++nf) acc[mf][nf] = zz;

    f32x4 pa0[2], pa1[2];
    bf16x8 pab[2];
    bf16x8 pb[4];

    auto issueA = [&](int k0) {
        if constexpr (AF32) {
#pragma unroll
            for (int i = 0; i < 2; ++i) {
                const float* s = Af + (size_t)(bm0 + srow + 32 * i) * KK + k0 + sc * 8;
                pa0[i] = *(const f32x4*)s;
                pa1[i] = *(const f32x4*)(s + 4);
            }
        } else {
#pragma unroll
            for (int i = 0; i < 2; ++i)
                pab[i] = *(const bf16x8*)(Ab + (size_t)(bm0 + srow + 32 * i) * KK + k0 + sc * 8);
        }
    };
    auto issueB = [&](int k0) {
#pragma unroll
        for (int i = 0; i < 4; ++i)
            pb[i] = *(const bf16x8*)(Bt + (size_t)(bn0 + srow + 32 * i) * KK + k0 + sc * 8);
    };
    auto writeS = [&]() {
#pragma unroll
        for (int i = 0; i < 2; ++i) {
            bf16x8 t;
            if constexpr (AF32) {
#pragma unroll
                for (int j = 0; j < 4; ++j) {
                    t[j] = (bf16)pa0[i][j];
                    t[4 + j] = (bf16)pa1[i][j];
                }
            } else {
                t = pab[i];
            }
            *(bf16x8*)(AsB + (srow + 32 * i) * LDS_STRIDE + sc * 16) = t;
        }
#pragma unroll
        for (int i = 0; i < 4; ++i)
            *(bf16x8*)(BsB + (srow + 32 * i) * LDS_STRIDE + sc * 16) = pb[i];
    };

    issueA(0);
    issueB(0);
    for (int k0 = 0; k0 < KK; k0 += 64) {
        __syncthreads();
        writeS();
        int kn = (k0 + 64 < KK) ? k0 + 64 : k0;
        issueA(kn);
        issueB(kn);
        __syncthreads();
#pragma unroll
        for (int kk = 0; kk < 2; ++kk) {
            const int kb = kk * 64 + (g << 4);
            bf16x8 bfr[2];
#pragma unroll
            for (int nf = 0; nf < 2; ++nf) {
                int rn = w * 32 + nf * 16 + li;
                bfr[nf] = *(const bf16x8*)(BsB + rn * LDS_STRIDE + kb);
            }
#pragma unroll
            for (int mf = 0; mf < 4; ++mf) {
                int rm = mf * 16 + li;
                bf16x8 afr = *(const bf16x8*)(AsB + rm * LDS_STRIDE + kb);
                acc[mf][0] = __builtin_amdgcn_mfma_f32_16x16x32_bf16(
                    afr, bfr[0], acc[mf][0], 0, 0, 0);
                acc[mf][1] = __builtin_amdgcn_mfma_f32_16x16x32_bf16(
                    afr, bfr[1], acc[mf][1], 0, 0, 0);
            }
        }
    }
}

// fused Q/K/V projections: one launch, grid (64, 8, 3)
__global__ __launch_bounds__(256) void k_proj3(const float* __restrict__ q,
                                               const float* __restrict__ k,
                                               const float* __restrict__ v,
                                               const bf16* __restrict__ WqT,
                                               const bf16* __restrict__ WkT,
                                               const bf16* __restrict__ WvT,
                                               bf16* __restrict__ Qh,
                                               bf16* __restrict__ Kh,
                                               bf16* __restrict__ Vt) {
    __shared__ __align__(16) char AsB[64 * LDS_STRIDE];
    __shared__ __align__(16) char BsB[128 * LDS_STRIDE];
    const int z = blockIdx.z;
    const float* A = z == 0 ? q : z == 1 ? k : v;
    const bf16* Bt = z == 0 ? WqT : z == 1 ? WkT : WvT;
    const float scale = (z == 0) ? 0.125f * LOG2E : 1.0f;
    const int bm0 = blockIdx.x * 64, bn0 = blockIdx.y * 128;

    f32x4 acc[4][2];
    kb_core<true>(A, Bt, bm0, bn0, AsB, BsB, acc);

    const int tid = threadIdx.x, lane = tid & 63, w = tid >> 6;
    const int g = lane >> 4, li = lane & 15;

    if (z < 2) {
        bf16* C = (z == 0) ? Qh : Kh;
#pragma unroll
        for (int mf = 0; mf < 4; ++mf)
#pragma unroll
            for (int nf = 0; nf < 2; ++nf) {
                int n = bn0 + w * 32 + nf * 16 + li;
                int m0 = bm0 + mf * 16 + (g << 2);
#pragma unroll
                for (int r = 0; r < 4; ++r)
                    C[(size_t)(m0 + r) * NN + n] = (bf16)(acc[mf][nf][r] * scale);
            }
    } else {
#pragma unroll
        for (int mf = 0; mf < 4; ++mf)
#pragma unroll
            for (int nf = 0; nf < 2; ++nf) {
                int n = bn0 + w * 32 + nf * 16 + li;
                int m0 = bm0 + mf * 16 + (g << 2);
                int bq = m0 >> 11, tok = m0 & (N_ - 1);
                int hh = n >> 6, dv = n & 63;
                bf4 val;
#pragma unroll
                for (int r = 0; r < 4; ++r) val.v[r] = (bf16)acc[mf][nf][r];
                *(bf4*)(Vt + ((size_t)((bq * H_ + hh) * 64 + dv)) * N_ + tok) = val;
            }
    }
}

// output GEMM: out = Ob @ WoT^T + resid
__global__ __launch_bounds__(256) void k_out(const bf16* __restrict__ Ob,
                                             const bf16* __restrict__ WoT,
                                             float* __restrict__ outp,
                                             const float* __restrict__ resid) {
    __shared__ __align__(16) char AsB[64 * LDS_STRIDE];
    __shared__ __align__(16) char BsB[128 * LDS_STRIDE];
    const int bm0 = blockIdx.x * 64, bn0 = blockIdx.y * 128;

    f32x4 acc[4][2];
    kb_core<false>(Ob, WoT, bm0, bn0, AsB, BsB, acc);

    const int tid = threadIdx.x, lane = tid & 63, w = tid >> 6;
    const int g = lane >> 4, li = lane & 15;
#pragma unroll
    for (int mf = 0; mf < 4; ++mf)
#pragma unroll
        for (int nf = 0; nf < 2; ++nf) {
            int n = bn0 + w * 32 + nf * 16 + li;
            int m0 = bm0 + mf * 16 + (g << 2);
#pragma unroll
            for (int r = 0; r < 4; ++r) {
                size_t ix = (size_t)(m0 + r) * NN + n;
                outp[ix] = acc[mf][nf][r] + resid[ix];
            }
        }
}

// ---------------------------------------------------------------- attention
// R12/R15 structure verbatim + s_setprio(1) around MFMA clusters (T5: the two
// independent blocks per CU drift out of phase -> scheduler favors MFMA wave).
__global__ __launch_bounds__(256) void k_attn(const bf16* __restrict__ Qh,
                                              const bf16* __restrict__ Kh,
                                              const bf16* __restrict__ Vt,
                                              const uint32_t* __restrict__ bits,
                                              float* __restrict__ attnp,
                                              bf16* __restrict__ Ob) {
    __shared__ __align__(16) char Qs[64 * LDS_STRIDE];    //  9216
    __shared__ __align__(16) char Ks[128 * LDS_STRIDE];   // 18432
    __shared__ __align__(16) char Vs[64 * PSTR];          // 17408
    __shared__ __align__(16) char Ps[64 * PSTR];          // 17408
    const int tid = threadIdx.x, lane = tid & 63, w = tid >> 6;
    const int g = lane >> 4, li = lane & 15;
    const int p = blockIdx.x, h = blockIdx.y, b = blockIdx.z;
    const int srow = tid >> 3, sc = tid & 7;
    const int myrow = w * 16 + li;

    const size_t kbase = ((size_t)b * N_) * D_ + h * 64;
    const size_t vbase = ((size_t)(b * H_ + h) * 64) * N_;
    f32x4 zz = {0.f, 0.f, 0.f, 0.f};

    bf16x8 kr[4], vr[4];
    auto loadK = [&](int jt) {
#pragma unroll
        for (int i = 0; i < 4; ++i)
            kr[i] = *(const bf16x8*)(Kh + kbase +
                (size_t)(jt * 128 + srow + 32 * i) * D_ + sc * 8);
    };
    auto writeK = [&]() {
#pragma unroll
        for (int i = 0; i < 4; ++i)
            *(bf16x8*)(Ks + (srow + 32 * i) * LDS_STRIDE + sc * 16) = kr[i];
    };
    auto loadV = [&](int jt) {
#pragma unroll
        for (int c = 0; c < 4; ++c) {
            int row = srow + 32 * (c & 1);
            int cc = sc + 8 * (c >> 1);
            vr[c] = *(const bf16x8*)(Vt + vbase + (size_t)row * N_ + jt * 128 + cc * 8);
        }
    };
    auto writeV = [&]() {
#pragma unroll
        for (int c = 0; c < 4; ++c) {
            int row = srow + 32 * (c & 1);
            int cc = sc + 8 * (c >> 1);
            *(bf16x8*)(Vs + row * PSTR + cc * 16) = vr[c];
        }
    };

    for (int half = 0; half < 2; ++half) {
        const int qt = half ? (31 - p) : p;
        const int i0 = qt << 6;
        const int R = (qt + 2) >> 1;
        const size_t abase = (((size_t)b * H_ + h) * N_ + i0) * (size_t)N_;

        __syncthreads();
        {
            const bf16* qsrc = Qh + kbase + (size_t)(i0 + srow) * D_ + sc * 8;
            bf16x8 t0 = *(const bf16x8*)qsrc;
            bf16x8 t1 = *(const bf16x8*)(qsrc + (size_t)32 * D_);
            *(bf16x8*)(Qs + srow * LDS_STRIDE + sc * 16) = t0;
            *(bf16x8*)(Qs + (srow + 32) * LDS_STRIDE + sc * 16) = t1;
        }
        const uint32_t* mrow = bits + (((size_t)b * N_ + i0 + myrow) << 6);

        // ================= pass A: row stats =================
        float m = -1e30f, l = 0.f;
        loadK(0);
        for (int jt = 0; jt < R; ++jt) {
            __syncthreads();
            writeK();
            loadK((jt + 1 < R) ? jt + 1 : jt);
            uint4 mw = *(const uint4*)(mrow + (jt << 2));
            __syncthreads();

            f32x4 s[8];
#pragma unroll
            for (int mf = 0; mf < 8; ++mf) s[mf] = zz;
            __builtin_amdgcn_s_setprio(1);
#pragma unroll
            for (int kk = 0; kk < 2; ++kk) {
                const int kb = kk * 64 + (g << 4);
                bf16x8 qf = *(const bf16x8*)(Qs + myrow * LDS_STRIDE + kb);
#pragma unroll
                for (int mf = 0; mf < 8; ++mf) {
                    bf16x8 kf = *(const bf16x8*)(Ks + (mf * 16 + li) * LDS_STRIDE + kb);
                    s[mf] = __builtin_amdgcn_mfma_f32_16x16x32_bf16(kf, qf, s[mf], 0, 0, 0);
                }
            }
            __builtin_amdgcn_s_setprio(0);
            float tmax = m;
#pragma unroll
            for (int mf = 0; mf < 8; ++mf) {
                uint32_t wsel = (mf < 2) ? mw.x : (mf < 4) ? mw.y : (mf < 6) ? mw.z : mw.w;
#pragma unroll
                for (int r = 0; r < 4; ++r) {
                    int sh = (mf & 1) * 16 + g * 4 + r;
                    float xv = ((wsel >> sh) & 1) ? s[mf][r] : -1e9f;
                    s[mf][r] = xv;
                    tmax = fmaxf(tmax, xv);
                }
            }
            tmax = fmaxf(tmax, __shfl_xor(tmax, 16));
            tmax = fmaxf(tmax, __shfl_xor(tmax, 32));
            float ps = 0.f;
#pragma unroll
            for (int mf = 0; mf < 8; ++mf)
#pragma unroll
                for (int r = 0; r < 4; ++r) ps += exp2f(s[mf][r] - tmax);
            ps += __shfl_xor(ps, 16);
            ps += __shfl_xor(ps, 32);
            l = l * exp2f(m - tmax) + ps;
            m = tmax;
        }
        const float ml = m + __log2f(l);

        // ================= pass B: P + O =================
        f32x4 oacc[4];
#pragma unroll
        for (int nf = 0; nf < 4; ++nf) oacc[nf] = zz;

        loadK(0);
        loadV(0);
        for (int jt = 0; jt < R; ++jt) {
            __syncthreads();
            writeK();
            writeV();
            {
                int jn = (jt + 1 < R) ? jt + 1 : jt;
                loadK(jn);
                loadV(jn);
            }
            uint4 mw = *(const uint4*)(mrow + (jt << 2));
            __syncthreads();

            f32x4 s[8];
#pragma unroll
            for (int mf = 0; mf < 8; ++mf) s[mf] = zz;
            __builtin_amdgcn_s_setprio(1);
#pragma unroll
            for (int kk = 0; kk < 2; ++kk) {
                const int kb = kk * 64 + (g << 4);
                bf16x8 qf = *(const bf16x8*)(Qs + myrow * LDS_STRIDE + kb);
#pragma unroll
                for (int mf = 0; mf < 8; ++mf) {
                    bf16x8 kf = *(const bf16x8*)(Ks + (mf * 16 + li) * LDS_STRIDE + kb);
                    s[mf] = __builtin_amdgcn_mfma_f32_16x16x32_bf16(kf, qf, s[mf], 0, 0, 0);
                }
            }
            __builtin_amdgcn_s_setprio(0);

#pragma unroll
            for (int mf = 0; mf < 8; ++mf) {
                uint32_t wsel = (mf < 2) ? mw.x : (mf < 4) ? mw.y : (mf < 6) ? mw.z : mw.w;
#pragma unroll
                for (int r = 0; r < 4; ++r) {
                    int sh = (mf & 1) * 16 + g * 4 + r;
                    float xv = ((wsel >> sh) & 1) ? s[mf][r] : -1e9f;
                    s[mf][r] = exp2f(xv - ml);
                }
                *(f32x4*)(attnp + abase + (size_t)myrow * N_ + (jt << 7) + mf * 16 + g * 4) = s[mf];
                bf4 pk;
#pragma unroll
                for (int r = 0; r < 4; ++r) pk.v[r] = (bf16)s[mf][r];
                *(bf4*)(Ps + myrow * PSTR + (mf * 16 + g * 4) * 2) = pk;
            }
            __builtin_amdgcn_s_setprio(1);
#pragma unroll
            for (int kk = 0; kk < 4; ++kk) {
                const int kb = kk * 64 + (g << 4);
                bf16x8 pf = *(const bf16x8*)(Ps + myrow * PSTR + kb);
#pragma unroll
                for (int nf = 0; nf < 4; ++nf) {
                    bf16x8 vf = *(const bf16x8*)(Vs + (nf * 16 + li) * PSTR + kb);
                    oacc[nf] = __builtin_amdgcn_mfma_f32_16x16x32_bf16(pf, vf, oacc[nf], 0, 0, 0);
                }
            }
            __builtin_amdgcn_s_setprio(0);
        }
#pragma unroll
        for (int nf = 0; nf < 4; ++nf)
#pragma unroll
            for (int r = 0; r < 4; ++r) {
                int gi = i0 + w * 16 + g * 4 + r;
                Ob[((size_t)(b * N_ + gi)) * D_ + h * 64 + nf * 16 + li] = (bf16)oacc[nf][r];
            }
        int zc0 = R << 7;
        if (zc0 < N_) {
            int r = tid >> 2, tc = tid & 3;
            f32x4 z = zz;
            for (int c = zc0 + tc * 4; c < N_; c += 16)
                *(f32x4*)(attnp + abase + (size_t)r * N_ + c) = z;
        }
    }
}

// ---------------------------------------------------------------- layernorm
__global__ __launch_bounds__(256) void k_ln(float* __restrict__ out,
                                            const float* __restrict__ gamma,
                                            const float* __restrict__ beta) {
    const int row = blockIdx.x, t = threadIdx.x, lane = t & 63, w = t >> 6;
    float* p = out + (size_t)row * D_;
    f32x4 x = *(const f32x4*)(p + t * 4);
    float s = x[0] + x[1] + x[2] + x[3];
    float s2 = x[0] * x[0] + x[1] * x[1] + x[2] * x[2] + x[3] * x[3];
#pragma unroll
    for (int o = 1; o < 64; o <<= 1) {
        s += __shfl_xor(s, o);
        s2 += __shfl_xor(s2, o);
    }
    __shared__ float r1[4], r2[4];
    if (lane == 0) { r1[w] = s; r2[w] = s2; }
    __syncthreads();
    s = r1[0] + r1[1] + r1[2] + r1[3];
    s2 = r2[0] + r2[1] + r2[2] + r2[3];
    float mean = s * (1.f / D_);
    float var = s2 * (1.f / D_) - mean * mean;
    float rstd = rsqrtf(var + 1e-6f);
    f32x4 gv = *(const f32x4*)(gamma + t * 4);
    f32x4 bv = *(const f32x4*)(beta + t * 4);
    f32x4 y;
#pragma unroll
    for (int c = 0; c < 4; ++c) y[c] = (x[c] - mean) * rstd * gv[c] + bv[c];
    *(f32x4*)(p + t * 4) = y;
}

// ---------------------------------------------------------------- launch
extern "C" void kernel_launch(void* const* d_in, const int* in_sizes, int n_in,
                              void* d_out, int out_size, void* d_ws,
                              size_t ws_size, hipStream_t stream) {
    (void)in_sizes; (void)n_in; (void)out_size; (void)ws_size;
    const float* q = (const float*)d_in[0];
    const float* k = (const float*)d_in[1];
    const float* v = (const float*)d_in[2];
    const int* msk = (const int*)d_in[3];
    const float* Wq = (const float*)d_in[4];
    const float* Wk = (const float*)d_in[5];
    const float* Wv = (const float*)d_in[6];
    const float* Wo = (const float*)d_in[7];
    const float* gamma = (const float*)d_in[8];
    const float* beta = (const float*)d_in[9];

    float* outp = (float*)d_out;
    float* attnp = outp + (size_t)B_ * N_ * D_;

    const size_t U = (size_t)B_ * N_ * D_;
    const size_t W1 = (size_t)D_ * D_;
    bf16* ws = (bf16*)d_ws;
    bf16* WqT = ws;  ws += W1;
    bf16* WkT = ws;  ws += W1;
    bf16* WvT = ws;  ws += W1;
    bf16* WoT = ws;  ws += W1;
    bf16* Qh = ws;   ws += U;
    bf16* Kh = ws;   ws += U;
    bf16* Vt = ws;   ws += U;   // (B,H,DV,N)
    bf16* Ob = ws;   ws += U;
    uint32_t* bits = (uint32_t*)ws;  // 1 MB

    // 4096 wtt blocks + 16384 bits blocks in one launch
    k_prep<<<4096 + (B_ * N_ * N_ / 256), 256, 0, stream>>>(
        Wq, Wk, Wv, Wo, msk, WqT, WkT, WvT, WoT, bits);

    k_proj3<<<dim3(MM / 64, NN / 128, 3), 256, 0, stream>>>(q, k, v, WqT, WkT, WvT, Qh, Kh, Vt);

    k_attn<<<dim3(16, H_, B_), 256, 0, stream>>>(Qh, Kh, Vt, bits, attnp, Ob);

    k_out<<<dim3(MM / 64, NN / 128), 256, 0, stream>>>(Ob, WoT, outp, q);

    k_ln<<<B_ * N_, 256, 0, stream>>>(outp, gamma, beta);
}